// Round 1
// baseline (1516.476 us; speedup 1.0000x reference)
//
#include <hip/hip_runtime.h>
#include <math.h>

#define NN 50000
#define NE 800000
#define ET (NE + NN)
#define FIN 256
#define HIDC 256
#define OC 64
#define NH 4
#define NEG 0.2f

// ---- monotonic float<->uint encoding for atomic max on floats ----
__device__ __forceinline__ unsigned encf(float f) {
    unsigned b = __float_as_uint(f);
    return b ^ ((unsigned)((int)b >> 31) | 0x80000000u);
}
__device__ __forceinline__ float decf(unsigned u) {
    unsigned b = (u & 0x80000000u) ? (u ^ 0x80000000u) : ~u;
    return __uint_as_float(b);
}

#define ENC_NEG_INF 0x007FFFFFu  // encf(-INFINITY)

__global__ void k_init(unsigned* m1, float* d1, unsigned* m2, float* d2) {
    int i = blockIdx.x * blockDim.x + threadIdx.x;
    if (i < NN * NH) { m1[i] = ENC_NEG_INF; d1[i] = 0.f; }
    if (i < NN)      { m2[i] = ENC_NEG_INF; d2[i] = 0.f; }
}

// h1[NN,256] = x[NN,256] @ W1[256,256]; 256 thr/block, 16 rows/block
__global__ void k_gemm1(const float* __restrict__ x, const float* __restrict__ W,
                        float* __restrict__ h) {
    __shared__ float xs[16][FIN];
    int r0 = blockIdx.x * 16;
    int tid = threadIdx.x;
    for (int i = tid; i < 16 * FIN; i += 256) {
        int r = i >> 8, c = i & 255;
        int gr = r0 + r;
        xs[r][c] = (gr < NN) ? x[gr * FIN + c] : 0.f;
    }
    __syncthreads();
    int col = tid;
    float acc[16];
#pragma unroll
    for (int i = 0; i < 16; i++) acc[i] = 0.f;
    for (int k = 0; k < FIN; k++) {
        float wv = W[k * HIDC + col];
#pragma unroll
        for (int r = 0; r < 16; r++) acc[r] += xs[r][k] * wv;
    }
    for (int r = 0; r < 16; r++) {
        int gr = r0 + r;
        if (gr < NN) h[gr * HIDC + col] = acc[r];
    }
}

// h2[NN,64] = a[NN,256] @ W2[256,64]; 256 thr = (64 cols x 4 row-groups), 16 rows/block
__global__ void k_gemm2(const float* __restrict__ a, const float* __restrict__ W,
                        float* __restrict__ h) {
    __shared__ float as_[16][FIN];
    int r0 = blockIdx.x * 16;
    int tid = threadIdx.x;
    for (int i = tid; i < 16 * FIN; i += 256) {
        int r = i >> 8, c = i & 255;
        int gr = r0 + r;
        as_[r][c] = (gr < NN) ? a[gr * FIN + c] : 0.f;
    }
    __syncthreads();
    int c = tid & 63, g = tid >> 6;
    float acc[4] = {0.f, 0.f, 0.f, 0.f};
    for (int k = 0; k < FIN; k++) {
        float wv = W[k * OC + c];
#pragma unroll
        for (int r = 0; r < 4; r++) acc[r] += as_[g * 4 + r][k] * wv;
    }
    for (int r = 0; r < 4; r++) {
        int gr = r0 + g * 4 + r;
        if (gr < NN) h[gr * OC + c] = acc[r];
    }
}

// alpha for layer1: block = 1 node, 4 waves = 4 heads, 64 lanes = channels
__global__ void k_alpha1(const float* __restrict__ h, const float* __restrict__ a_s,
                         const float* __restrict__ a_d, float* __restrict__ as,
                         float* __restrict__ ad) {
    int n = blockIdx.x;
    int hh = threadIdx.x >> 6;
    int c = threadIdx.x & 63;
    float hv = h[n * HIDC + hh * 64 + c];
    float vs = hv * a_s[hh * 64 + c];
    float vd = hv * a_d[hh * 64 + c];
    for (int off = 32; off; off >>= 1) {
        vs += __shfl_xor(vs, off);
        vd += __shfl_xor(vd, off);
    }
    if (c == 0) { as[n * NH + hh] = vs; ad[n * NH + hh] = vd; }
}

// alpha for layer2: 4 nodes/block, 1 wave per node
__global__ void k_alpha2(const float* __restrict__ h, const float* __restrict__ a_s,
                         const float* __restrict__ a_d, float* __restrict__ as,
                         float* __restrict__ ad) {
    int n = blockIdx.x * 4 + (threadIdx.x >> 6);
    int c = threadIdx.x & 63;
    if (n >= NN) return;
    float hv = h[n * OC + c];
    float vs = hv * a_s[c];
    float vd = hv * a_d[c];
    for (int off = 32; off; off >>= 1) {
        vs += __shfl_xor(vs, off);
        vd += __shfl_xor(vd, off);
    }
    if (c == 0) { as[n] = vs; ad[n] = vd; }
}

template <int H>
__global__ void k_emax(const int* __restrict__ ei, const float* __restrict__ as,
                       const float* __restrict__ ad, unsigned* __restrict__ m) {
    int e = blockIdx.x * blockDim.x + threadIdx.x;
    if (e >= ET) return;
    int s, d;
    if (e < NE) { s = ei[e]; d = ei[NE + e]; } else { s = d = e - NE; }
#pragma unroll
    for (int h = 0; h < H; h++) {
        float el = as[s * H + h] + ad[d * H + h];
        el = el > 0.f ? el : NEG * el;
        atomicMax(&m[d * H + h], encf(el));
    }
}

template <int H>
__global__ void k_ew(const int* __restrict__ ei, const float* __restrict__ as,
                     const float* __restrict__ ad, const unsigned* __restrict__ m,
                     float* __restrict__ w, float* __restrict__ den) {
    int e = blockIdx.x * blockDim.x + threadIdx.x;
    if (e >= ET) return;
    int s, d;
    if (e < NE) { s = ei[e]; d = ei[NE + e]; } else { s = d = e - NE; }
#pragma unroll
    for (int h = 0; h < H; h++) {
        float el = as[s * H + h] + ad[d * H + h];
        el = el > 0.f ? el : NEG * el;
        float ww = expf(el - decf(m[d * H + h]));
        w[e * H + h] = ww;
        atomicAdd(&den[d * H + h], ww);
    }
}

// layer1 aggregation: 1 block = 1 edge, 256 threads = 256 channels (4 heads x 64)
__global__ void k_agg1(const int* __restrict__ ei, const float* __restrict__ h,
                       const float* __restrict__ w, const float* __restrict__ den,
                       float* __restrict__ out) {
    int e = blockIdx.x;
    int c = threadIdx.x;
    int s, d;
    if (e < NE) { s = ei[e]; d = ei[NE + e]; } else { s = d = e - NE; }
    int hh = c >> 6;
    float att = w[e * NH + hh] / (den[d * NH + hh] + 1e-16f);
    atomicAdd(&out[d * HIDC + c], att * h[s * HIDC + c]);
}

// layer2 aggregation: 1 block = 1 edge, 64 threads
__global__ void k_agg2(const int* __restrict__ ei, const float* __restrict__ h,
                       const float* __restrict__ w, const float* __restrict__ den,
                       float* __restrict__ out) {
    int e = blockIdx.x;
    int c = threadIdx.x;
    int s, d;
    if (e < NE) { s = ei[e]; d = ei[NE + e]; } else { s = d = e - NE; }
    float att = w[e] / (den[d] + 1e-16f);
    atomicAdd(&out[d * OC + c], att * h[s * OC + c]);
}

__global__ void k_elu(float* __restrict__ a, const float* __restrict__ b) {
    int i = blockIdx.x * blockDim.x + threadIdx.x;
    if (i >= NN * HIDC) return;
    float v = a[i] + b[i & 255];
    a[i] = v > 0.f ? v : expm1f(v);
}

__global__ void k_b2(float* __restrict__ o, const float* __restrict__ b) {
    int i = blockIdx.x * blockDim.x + threadIdx.x;
    if (i >= NN * OC) return;
    o[i] += b[i & 63];
}

extern "C" void kernel_launch(void* const* d_in, const int* in_sizes, int n_in,
                              void* d_out, int out_size, void* d_ws, size_t ws_size,
                              hipStream_t stream) {
    const float* x   = (const float*)d_in[0];
    const int*   ei  = (const int*)d_in[1];   // assumed int32 (JAX x64 disabled)
    const float* W1  = (const float*)d_in[2];
    const float* aS1 = (const float*)d_in[3];
    const float* aD1 = (const float*)d_in[4];
    const float* b1  = (const float*)d_in[5];
    const float* W2  = (const float*)d_in[6];
    const float* aS2 = (const float*)d_in[7];
    const float* aD2 = (const float*)d_in[8];
    const float* b2  = (const float*)d_in[9];
    float* out = (float*)d_out;

    char* p = (char*)d_ws;
    auto alloc = [&](size_t nbytes) {
        char* r = p;
        p += (nbytes + 255) & ~(size_t)255;
        return r;
    };
    float*    h1   = (float*)alloc((size_t)NN * HIDC * 4);
    float*    out1 = (float*)alloc((size_t)NN * HIDC * 4);  // becomes ELU activations
    float*    h2   = (float*)alloc((size_t)NN * OC * 4);
    float*    as1  = (float*)alloc((size_t)NN * NH * 4);
    float*    ad1  = (float*)alloc((size_t)NN * NH * 4);
    unsigned* m1   = (unsigned*)alloc((size_t)NN * NH * 4);
    float*    den1 = (float*)alloc((size_t)NN * NH * 4);
    float*    w1   = (float*)alloc((size_t)ET * NH * 4);
    float*    as2  = (float*)alloc((size_t)NN * 4);
    float*    ad2  = (float*)alloc((size_t)NN * 4);
    unsigned* m2   = (unsigned*)alloc((size_t)NN * 4);
    float*    den2 = (float*)alloc((size_t)NN * 4);
    float*    w2   = (float*)alloc((size_t)ET * 4);

    hipMemsetAsync(out1, 0, (size_t)NN * HIDC * 4, stream);
    hipMemsetAsync(out, 0, (size_t)NN * OC * 4, stream);

    k_init<<<(NN * NH + 255) / 256, 256, 0, stream>>>(m1, den1, m2, den2);

    // ---- layer 1 ----
    k_gemm1<<<(NN + 15) / 16, 256, 0, stream>>>(x, W1, h1);
    k_alpha1<<<NN, 256, 0, stream>>>(h1, aS1, aD1, as1, ad1);
    k_emax<NH><<<(ET + 255) / 256, 256, 0, stream>>>(ei, as1, ad1, m1);
    k_ew<NH><<<(ET + 255) / 256, 256, 0, stream>>>(ei, as1, ad1, m1, w1, den1);
    k_agg1<<<ET, 256, 0, stream>>>(ei, h1, w1, den1, out1);
    k_elu<<<(NN * HIDC + 255) / 256, 256, 0, stream>>>(out1, b1);

    // ---- layer 2 ----
    k_gemm2<<<(NN + 15) / 16, 256, 0, stream>>>(out1, W2, h2);
    k_alpha2<<<(NN + 3) / 4, 256, 0, stream>>>(h2, aS2, aD2, as2, ad2);
    k_emax<1><<<(ET + 255) / 256, 256, 0, stream>>>(ei, as2, ad2, m2);
    k_ew<1><<<(ET + 255) / 256, 256, 0, stream>>>(ei, as2, ad2, m2, w2, den2);
    k_agg2<<<ET, 64, 0, stream>>>(ei, h2, w2, den2, out);
    k_b2<<<(NN * OC + 255) / 256, 256, 0, stream>>>(out, b2);
}

// Round 3
// 559.343 us; speedup vs baseline: 2.7112x; 2.7112x over previous
//
#include <hip/hip_runtime.h>
#include <math.h>

#define NN 50000
#define NE 800000
#define ET (NE + NN)
#define FIN 256
#define HIDC 256
#define OC 64
#define NH 4
#define NEG 0.2f
#define CAP 96   // max in-degree bucket capacity (Poisson(17) tail @95 ~ 0)

// ---- fused histogram + bucket scatter: esrc[d*CAP + k] = src ----
__global__ void k_scatter(const int* __restrict__ ei, int* __restrict__ cnt,
                          int* __restrict__ esrc) {
    int e = blockIdx.x * blockDim.x + threadIdx.x;
    if (e >= ET) return;
    int s, d;
    if (e < NE) { s = ei[e]; d = ei[NE + e]; } else { s = d = e - NE; }
    int k = atomicAdd(&cnt[d], 1);
    if (k < CAP) esrc[(size_t)d * CAP + k] = s;
}

// ============ GEMMs (fp32) ============

__global__ void k_gemm1(const float* __restrict__ x, const float* __restrict__ W,
                        float* __restrict__ h) {
    __shared__ float xs[16][FIN];
    int r0 = blockIdx.x * 16;
    int tid = threadIdx.x;
    for (int i = tid; i < 16 * FIN; i += 256) {
        int r = i >> 8, c = i & 255;
        int gr = r0 + r;
        xs[r][c] = (gr < NN) ? x[gr * FIN + c] : 0.f;
    }
    __syncthreads();
    int col = tid;
    float acc[16];
#pragma unroll
    for (int i = 0; i < 16; i++) acc[i] = 0.f;
    for (int k = 0; k < FIN; k++) {
        float wv = W[k * HIDC + col];
#pragma unroll
        for (int r = 0; r < 16; r++) acc[r] += xs[r][k] * wv;
    }
    for (int r = 0; r < 16; r++) {
        int gr = r0 + r;
        if (gr < NN) h[gr * HIDC + col] = acc[r];
    }
}

__global__ void k_gemm2(const float* __restrict__ a, const float* __restrict__ W,
                        float* __restrict__ h) {
    __shared__ float as_[16][FIN];
    int r0 = blockIdx.x * 16;
    int tid = threadIdx.x;
    for (int i = tid; i < 16 * FIN; i += 256) {
        int r = i >> 8, c = i & 255;
        int gr = r0 + r;
        as_[r][c] = (gr < NN) ? a[gr * FIN + c] : 0.f;
    }
    __syncthreads();
    int c = tid & 63, g = tid >> 6;
    float acc[4] = {0.f, 0.f, 0.f, 0.f};
    for (int k = 0; k < FIN; k++) {
        float wv = W[k * OC + c];
#pragma unroll
        for (int r = 0; r < 4; r++) acc[r] += as_[g * 4 + r][k] * wv;
    }
    for (int r = 0; r < 4; r++) {
        int gr = r0 + g * 4 + r;
        if (gr < NN) h[gr * OC + c] = acc[r];
    }
}

// ============ alpha dot products ============

__global__ void k_alpha1(const float* __restrict__ h, const float* __restrict__ a_s,
                         const float* __restrict__ a_d, float* __restrict__ as,
                         float* __restrict__ ad) {
    int n = blockIdx.x;
    int hh = threadIdx.x >> 6;
    int c = threadIdx.x & 63;
    float hv = h[n * HIDC + hh * 64 + c];
    float vs = hv * a_s[hh * 64 + c];
    float vd = hv * a_d[hh * 64 + c];
    for (int off = 32; off; off >>= 1) {
        vs += __shfl_xor(vs, off);
        vd += __shfl_xor(vd, off);
    }
    if (c == 0) { as[n * NH + hh] = vs; ad[n * NH + hh] = vd; }
}

__global__ void k_alpha2(const float* __restrict__ h, const float* __restrict__ a_s,
                         const float* __restrict__ a_d, float* __restrict__ as,
                         float* __restrict__ ad) {
    int n = blockIdx.x * 4 + (threadIdx.x >> 6);
    int c = threadIdx.x & 63;
    if (n >= NN) return;
    float hv = h[n * OC + c];
    float vs = hv * a_s[c];
    float vd = hv * a_d[c];
    for (int off = 32; off; off >>= 1) {
        vs += __shfl_xor(vs, off);
        vd += __shfl_xor(vd, off);
    }
    if (c == 0) { as[n] = vs; ad[n] = vd; }
}

// ============ per-node softmax stats (thread per node, two passes over bucket) ============

template <int H>
__global__ void k_attn(const int* __restrict__ cnt, const int* __restrict__ esrc,
                       const float* __restrict__ as, const float* __restrict__ ad,
                       float* __restrict__ m, float* __restrict__ rden) {
    int n = blockIdx.x * blockDim.x + threadIdx.x;
    if (n >= NN) return;
    float adv[H], mm[H], dd[H];
#pragma unroll
    for (int h = 0; h < H; h++) { adv[h] = ad[n * H + h]; mm[h] = -INFINITY; }
    int deg = cnt[n];
    deg = deg < CAP ? deg : CAP;
    const int* bucket = &esrc[(size_t)n * CAP];
    for (int j = 0; j < deg; j++) {
        int s = bucket[j];
#pragma unroll
        for (int h = 0; h < H; h++) {
            float e = as[s * H + h] + adv[h];
            e = e > 0.f ? e : NEG * e;
            mm[h] = fmaxf(mm[h], e);
        }
    }
#pragma unroll
    for (int h = 0; h < H; h++) dd[h] = 0.f;
    for (int j = 0; j < deg; j++) {
        int s = bucket[j];
#pragma unroll
        for (int h = 0; h < H; h++) {
            float e = as[s * H + h] + adv[h];
            e = e > 0.f ? e : NEG * e;
            dd[h] += expf(e - mm[h]);
        }
    }
#pragma unroll
    for (int h = 0; h < H; h++) {
        m[n * H + h] = mm[h];
        rden[n * H + h] = 1.f / (dd[h] + 1e-16f);
    }
}

// ============ aggregation: one wave per node, gather over bucket ============

__global__ void k_agg1g(const int* __restrict__ cnt, const int* __restrict__ esrc,
                        const float* __restrict__ h, const float* __restrict__ as,
                        const float* __restrict__ ad, const float* __restrict__ m,
                        const float* __restrict__ rden, const float* __restrict__ bias,
                        float* __restrict__ out) {
    int n = blockIdx.x * 4 + (threadIdx.x >> 6);
    int c = threadIdx.x & 63;
    if (n >= NN) return;
    float4 adv = *(const float4*)&ad[n * NH];
    float4 mv = *(const float4*)&m[n * NH];
    float4 rd = *(const float4*)&rden[n * NH];
    float acc0 = 0.f, acc1 = 0.f, acc2 = 0.f, acc3 = 0.f;
    int deg = cnt[n];
    deg = deg < CAP ? deg : CAP;
    const int* bucket = &esrc[(size_t)n * CAP];
    for (int j = 0; j < deg; j++) {
        int s = bucket[j];
        float4 av = *(const float4*)&as[s * NH];
        float e0f = av.x + adv.x; e0f = e0f > 0.f ? e0f : NEG * e0f;
        float e1f = av.y + adv.y; e1f = e1f > 0.f ? e1f : NEG * e1f;
        float e2f = av.z + adv.z; e2f = e2f > 0.f ? e2f : NEG * e2f;
        float e3f = av.w + adv.w; e3f = e3f > 0.f ? e3f : NEG * e3f;
        float w0 = expf(e0f - mv.x) * rd.x;
        float w1 = expf(e1f - mv.y) * rd.y;
        float w2 = expf(e2f - mv.z) * rd.z;
        float w3 = expf(e3f - mv.w) * rd.w;
        const float* hr = &h[(size_t)s * HIDC];
        acc0 += w0 * hr[c];
        acc1 += w1 * hr[64 + c];
        acc2 += w2 * hr[128 + c];
        acc3 += w3 * hr[192 + c];
    }
    float v;
    v = acc0 + bias[c];       out[n * HIDC + c]       = v > 0.f ? v : expm1f(v);
    v = acc1 + bias[64 + c];  out[n * HIDC + 64 + c]  = v > 0.f ? v : expm1f(v);
    v = acc2 + bias[128 + c]; out[n * HIDC + 128 + c] = v > 0.f ? v : expm1f(v);
    v = acc3 + bias[192 + c]; out[n * HIDC + 192 + c] = v > 0.f ? v : expm1f(v);
}

__global__ void k_agg2g(const int* __restrict__ cnt, const int* __restrict__ esrc,
                        const float* __restrict__ h, const float* __restrict__ as,
                        const float* __restrict__ ad, const float* __restrict__ m,
                        const float* __restrict__ rden, const float* __restrict__ bias,
                        float* __restrict__ out) {
    int n = blockIdx.x * 4 + (threadIdx.x >> 6);
    int c = threadIdx.x & 63;
    if (n >= NN) return;
    float adv = ad[n], mv = m[n], rd = rden[n];
    float acc = 0.f;
    int deg = cnt[n];
    deg = deg < CAP ? deg : CAP;
    const int* bucket = &esrc[(size_t)n * CAP];
    for (int j = 0; j < deg; j++) {
        int s = bucket[j];
        float e = as[s] + adv;
        e = e > 0.f ? e : NEG * e;
        acc += expf(e - mv) * rd * h[(size_t)s * OC + c];
    }
    out[n * OC + c] = acc + bias[c];
}

extern "C" void kernel_launch(void* const* d_in, const int* in_sizes, int n_in,
                              void* d_out, int out_size, void* d_ws, size_t ws_size,
                              hipStream_t stream) {
    const float* x   = (const float*)d_in[0];
    const int*   ei  = (const int*)d_in[1];
    const float* W1  = (const float*)d_in[2];
    const float* aS1 = (const float*)d_in[3];
    const float* aD1 = (const float*)d_in[4];
    const float* b1  = (const float*)d_in[5];
    const float* W2  = (const float*)d_in[6];
    const float* aS2 = (const float*)d_in[7];
    const float* aD2 = (const float*)d_in[8];
    const float* b2  = (const float*)d_in[9];
    float* out = (float*)d_out;

    char* p = (char*)d_ws;
    auto alloc = [&](size_t nbytes) {
        char* r = p;
        p += (nbytes + 255) & ~(size_t)255;
        return r;
    };
    float* h1   = (float*)alloc((size_t)NN * HIDC * 4);
    float* act1 = (float*)alloc((size_t)NN * HIDC * 4);
    float* h2   = (float*)alloc((size_t)NN * OC * 4);
    float* as1  = (float*)alloc((size_t)NN * NH * 4);
    float* ad1  = (float*)alloc((size_t)NN * NH * 4);
    float* m1   = (float*)alloc((size_t)NN * NH * 4);
    float* rd1  = (float*)alloc((size_t)NN * NH * 4);
    float* as2  = (float*)alloc((size_t)NN * 4);
    float* ad2  = (float*)alloc((size_t)NN * 4);
    float* m2   = (float*)alloc((size_t)NN * 4);
    float* rd2  = (float*)alloc((size_t)NN * 4);
    int*   cnt  = (int*)alloc((size_t)NN * 4);
    int*   esrc = (int*)alloc((size_t)NN * CAP * 4);

    hipMemsetAsync(cnt, 0, (size_t)NN * 4, stream);

    // ---- bucket CSR build (shared by both layers) ----
    k_scatter<<<(ET + 255) / 256, 256, 0, stream>>>(ei, cnt, esrc);

    // ---- layer 1 ----
    k_gemm1<<<(NN + 15) / 16, 256, 0, stream>>>(x, W1, h1);
    k_alpha1<<<NN, 256, 0, stream>>>(h1, aS1, aD1, as1, ad1);
    k_attn<NH><<<(NN + 255) / 256, 256, 0, stream>>>(cnt, esrc, as1, ad1, m1, rd1);
    k_agg1g<<<(NN + 3) / 4, 256, 0, stream>>>(cnt, esrc, h1, as1, ad1, m1, rd1, b1, act1);

    // ---- layer 2 ----
    k_gemm2<<<(NN + 15) / 16, 256, 0, stream>>>(act1, W2, h2);
    k_alpha2<<<(NN + 3) / 4, 256, 0, stream>>>(h2, aS2, aD2, as2, ad2);
    k_attn<1><<<(NN + 255) / 256, 256, 0, stream>>>(cnt, esrc, as2, ad2, m2, rd2);
    k_agg2g<<<(NN + 3) / 4, 256, 0, stream>>>(cnt, esrc, h2, as2, ad2, m2, rd2, b2, out);
}

// Round 4
// 425.991 us; speedup vs baseline: 3.5599x; 1.3130x over previous
//
#include <hip/hip_runtime.h>
#include <math.h>

#define NN 50000
#define NE 800000
#define ET (NE + NN)
#define FIN 256
#define HIDC 256
#define OC 64
#define NH 4
#define NEG 0.2f
#define CAP 96
#define NSTRIPES (NN / 16)  // 3125

typedef __attribute__((ext_vector_type(8))) short bf16x8;
typedef __attribute__((ext_vector_type(4))) float f32x4;

__device__ __forceinline__ unsigned short f2bf(float f) {
    unsigned u = __float_as_uint(f);
    unsigned r = (u + 0x7FFFu + ((u >> 16) & 1u)) >> 16;
    return (unsigned short)r;
}

// ---- fused histogram + bucket scatter ----
__global__ void k_scatter(const int* __restrict__ ei, int* __restrict__ cnt,
                          int* __restrict__ esrc) {
    int e = blockIdx.x * blockDim.x + threadIdx.x;
    if (e >= ET) return;
    int s, d;
    if (e < NE) { s = ei[e]; d = ei[NE + e]; } else { s = d = e - NE; }
    int k = atomicAdd(&cnt[d], 1);
    if (k < CAP) esrc[(size_t)d * CAP + k] = s;
}

// ---- f32 -> bf16 convert (8 elems/thread) ----
__global__ void k_cvt(const float* __restrict__ x, unsigned short* __restrict__ xb,
                      int n) {
    int i = (blockIdx.x * 256 + threadIdx.x) * 8;
    if (i >= n) return;
    float4 f0 = *(const float4*)&x[i];
    float4 f1 = *(const float4*)&x[i + 4];
    uint4 o;
    o.x = (unsigned)f2bf(f0.x) | ((unsigned)f2bf(f0.y) << 16);
    o.y = (unsigned)f2bf(f0.z) | ((unsigned)f2bf(f0.w) << 16);
    o.z = (unsigned)f2bf(f1.x) | ((unsigned)f2bf(f1.y) << 16);
    o.w = (unsigned)f2bf(f1.z) | ((unsigned)f2bf(f1.w) << 16);
    *(uint4*)&xb[i] = o;
}

// ---- pack W [256][N] f32 -> MFMA B-fragment order bf16 ----
// Bp[(((hy*8+ks)*NTL+ntl)*64+lane)*8 + i] = W[(ks*32+(lane>>4)*8+i)*N + hy*NTL*16+ntl*16+(lane&15)]
__global__ void k_pack(const float* __restrict__ W, unsigned short* __restrict__ Bp,
                       int N, int NTL, int total) {
    int t = blockIdx.x * 256 + threadIdx.x;
    if (t >= total) return;
    int lane = t & 63;
    int ntl = (t >> 6) % NTL;
    int ks = ((t >> 6) / NTL) & 7;
    int hy = t / (64 * NTL * 8);
    int col = hy * NTL * 16 + ntl * 16 + (lane & 15);
    int k0 = ks * 32 + (lane >> 4) * 8;
#pragma unroll
    for (int i = 0; i < 8; i++) Bp[(size_t)t * 8 + i] = f2bf(W[(k0 + i) * N + col]);
}

// ---- bf16 MFMA GEMM: A[NN][256] bf16 row-major, Bp packed; D f32 [NN][N] ----
// wave computes 16 rows x NTL*16 cols; whole B(half) staged in LDS.
template <int NTL>
__global__ void __launch_bounds__(256) k_gemm_mfma(const unsigned short* __restrict__ A,
                                                   const unsigned short* __restrict__ Bp,
                                                   float* __restrict__ D, int N) {
    constexpr int TOT = 8 * NTL * 64 * 8;  // ushorts per half
    __shared__ unsigned short lds[TOT];
    const unsigned short* src = Bp + (size_t)blockIdx.y * TOT;
    for (int i = threadIdx.x * 8; i < TOT; i += 256 * 8)
        *(uint4*)&lds[i] = *(const uint4*)&src[i];
    __syncthreads();
    int wave = threadIdx.x >> 6, lane = threadIdx.x & 63;
    int l15 = lane & 15, lh = lane >> 4;
    int coloff = blockIdx.y * NTL * 16;
    for (int st = blockIdx.x * 4 + wave; st < NSTRIPES; st += gridDim.x * 4) {
        const unsigned short* arow = A + (size_t)(st * 16 + l15) * 256 + lh * 8;
        f32x4 acc[NTL];
#pragma unroll
        for (int t = 0; t < NTL; t++) acc[t] = (f32x4){0.f, 0.f, 0.f, 0.f};
#pragma unroll
        for (int ks = 0; ks < 8; ks++) {
            bf16x8 a = *(const bf16x8*)(arow + ks * 32);
#pragma unroll
            for (int nt = 0; nt < NTL; nt++) {
                bf16x8 b = *(const bf16x8*)&lds[((size_t)(ks * NTL + nt) * 64 + lane) * 8];
                acc[nt] = __builtin_amdgcn_mfma_f32_16x16x32_bf16(a, b, acc[nt], 0, 0, 0);
            }
        }
        float* dbase = D + (size_t)st * 16 * N + coloff;
#pragma unroll
        for (int nt = 0; nt < NTL; nt++)
#pragma unroll
            for (int r = 0; r < 4; r++)
                dbase[(lh * 4 + r) * N + nt * 16 + l15] = acc[nt][r];
    }
}

// ============ alpha dot products ============

__global__ void k_alpha1(const float* __restrict__ h, const float* __restrict__ a_s,
                         const float* __restrict__ a_d, float* __restrict__ as,
                         float* __restrict__ ad) {
    int n = blockIdx.x;
    int hh = threadIdx.x >> 6;
    int c = threadIdx.x & 63;
    float hv = h[n * HIDC + hh * 64 + c];
    float vs = hv * a_s[hh * 64 + c];
    float vd = hv * a_d[hh * 64 + c];
    for (int off = 32; off; off >>= 1) {
        vs += __shfl_xor(vs, off);
        vd += __shfl_xor(vd, off);
    }
    if (c == 0) { as[n * NH + hh] = vs; ad[n * NH + hh] = vd; }
}

__global__ void k_alpha2(const float* __restrict__ h, const float* __restrict__ a_s,
                         const float* __restrict__ a_d, float* __restrict__ as,
                         float* __restrict__ ad) {
    int n = blockIdx.x * 4 + (threadIdx.x >> 6);
    int c = threadIdx.x & 63;
    if (n >= NN) return;
    float hv = h[n * OC + c];
    float vs = hv * a_s[c];
    float vd = hv * a_d[c];
    for (int off = 32; off; off >>= 1) {
        vs += __shfl_xor(vs, off);
        vd += __shfl_xor(vd, off);
    }
    if (c == 0) { as[n] = vs; ad[n] = vd; }
}

// ============ per-node softmax stats ============

template <int H>
__global__ void k_attn(const int* __restrict__ cnt, const int* __restrict__ esrc,
                       const float* __restrict__ as, const float* __restrict__ ad,
                       float* __restrict__ m, float* __restrict__ rden) {
    int n = blockIdx.x * blockDim.x + threadIdx.x;
    if (n >= NN) return;
    float adv[H], mm[H], dd[H];
#pragma unroll
    for (int h = 0; h < H; h++) { adv[h] = ad[n * H + h]; mm[h] = -INFINITY; }
    int deg = cnt[n];
    deg = deg < CAP ? deg : CAP;
    const int* bucket = &esrc[(size_t)n * CAP];
    for (int j = 0; j < deg; j++) {
        int s = bucket[j];
#pragma unroll
        for (int h = 0; h < H; h++) {
            float e = as[s * H + h] + adv[h];
            e = e > 0.f ? e : NEG * e;
            mm[h] = fmaxf(mm[h], e);
        }
    }
#pragma unroll
    for (int h = 0; h < H; h++) dd[h] = 0.f;
    for (int j = 0; j < deg; j++) {
        int s = bucket[j];
#pragma unroll
        for (int h = 0; h < H; h++) {
            float e = as[s * H + h] + adv[h];
            e = e > 0.f ? e : NEG * e;
            dd[h] += expf(e - mm[h]);
        }
    }
#pragma unroll
    for (int h = 0; h < H; h++) {
        m[n * H + h] = mm[h];
        rden[n * H + h] = 1.f / (dd[h] + 1e-16f);
    }
}

// ============ aggregation ============

// layer1: fused +bias, ELU, bf16 store (act1 only feeds GEMM2 which is bf16 anyway)
__global__ void k_agg1g(const int* __restrict__ cnt, const int* __restrict__ esrc,
                        const float* __restrict__ h, const float* __restrict__ as,
                        const float* __restrict__ ad, const float* __restrict__ m,
                        const float* __restrict__ rden, const float* __restrict__ bias,
                        unsigned short* __restrict__ out) {
    int n = blockIdx.x * 4 + (threadIdx.x >> 6);
    int c = threadIdx.x & 63;
    if (n >= NN) return;
    float4 adv = *(const float4*)&ad[n * NH];
    float4 mv = *(const float4*)&m[n * NH];
    float4 rd = *(const float4*)&rden[n * NH];
    float acc0 = 0.f, acc1 = 0.f, acc2 = 0.f, acc3 = 0.f;
    int deg = cnt[n];
    deg = deg < CAP ? deg : CAP;
    const int* bucket = &esrc[(size_t)n * CAP];
    for (int j = 0; j < deg; j++) {
        int s = bucket[j];
        float4 av = *(const float4*)&as[s * NH];
        float e0f = av.x + adv.x; e0f = e0f > 0.f ? e0f : NEG * e0f;
        float e1f = av.y + adv.y; e1f = e1f > 0.f ? e1f : NEG * e1f;
        float e2f = av.z + adv.z; e2f = e2f > 0.f ? e2f : NEG * e2f;
        float e3f = av.w + adv.w; e3f = e3f > 0.f ? e3f : NEG * e3f;
        float w0 = expf(e0f - mv.x) * rd.x;
        float w1 = expf(e1f - mv.y) * rd.y;
        float w2 = expf(e2f - mv.z) * rd.z;
        float w3 = expf(e3f - mv.w) * rd.w;
        const float* hr = &h[(size_t)s * HIDC];
        acc0 += w0 * hr[c];
        acc1 += w1 * hr[64 + c];
        acc2 += w2 * hr[128 + c];
        acc3 += w3 * hr[192 + c];
    }
    float v;
    v = acc0 + bias[c];       out[n * HIDC + c]       = f2bf(v > 0.f ? v : expm1f(v));
    v = acc1 + bias[64 + c];  out[n * HIDC + 64 + c]  = f2bf(v > 0.f ? v : expm1f(v));
    v = acc2 + bias[128 + c]; out[n * HIDC + 128 + c] = f2bf(v > 0.f ? v : expm1f(v));
    v = acc3 + bias[192 + c]; out[n * HIDC + 192 + c] = f2bf(v > 0.f ? v : expm1f(v));
}

__global__ void k_agg2g(const int* __restrict__ cnt, const int* __restrict__ esrc,
                        const float* __restrict__ h, const float* __restrict__ as,
                        const float* __restrict__ ad, const float* __restrict__ m,
                        const float* __restrict__ rden, const float* __restrict__ bias,
                        float* __restrict__ out) {
    int n = blockIdx.x * 4 + (threadIdx.x >> 6);
    int c = threadIdx.x & 63;
    if (n >= NN) return;
    float adv = ad[n], mv = m[n], rd = rden[n];
    float acc = 0.f;
    int deg = cnt[n];
    deg = deg < CAP ? deg : CAP;
    const int* bucket = &esrc[(size_t)n * CAP];
    for (int j = 0; j < deg; j++) {
        int s = bucket[j];
        float e = as[s] + adv;
        e = e > 0.f ? e : NEG * e;
        acc += expf(e - mv) * rd * h[(size_t)s * OC + c];
    }
    out[n * OC + c] = acc + bias[c];
}

extern "C" void kernel_launch(void* const* d_in, const int* in_sizes, int n_in,
                              void* d_out, int out_size, void* d_ws, size_t ws_size,
                              hipStream_t stream) {
    const float* x   = (const float*)d_in[0];
    const int*   ei  = (const int*)d_in[1];
    const float* W1  = (const float*)d_in[2];
    const float* aS1 = (const float*)d_in[3];
    const float* aD1 = (const float*)d_in[4];
    const float* b1  = (const float*)d_in[5];
    const float* W2  = (const float*)d_in[6];
    const float* aS2 = (const float*)d_in[7];
    const float* aD2 = (const float*)d_in[8];
    const float* b2  = (const float*)d_in[9];
    float* out = (float*)d_out;

    char* p = (char*)d_ws;
    auto alloc = [&](size_t nbytes) {
        char* r = p;
        p += (nbytes + 255) & ~(size_t)255;
        return r;
    };
    float*          h1    = (float*)alloc((size_t)NN * HIDC * 4);
    unsigned short* xb    = (unsigned short*)alloc((size_t)NN * FIN * 2);
    unsigned short* act1b = (unsigned short*)alloc((size_t)NN * HIDC * 2);
    float*          h2    = (float*)alloc((size_t)NN * OC * 4);
    unsigned short* Bp1   = (unsigned short*)alloc((size_t)2 * 8 * 8 * 64 * 8 * 2);
    unsigned short* Bp2   = (unsigned short*)alloc((size_t)1 * 8 * 4 * 64 * 8 * 2);
    float* as1  = (float*)alloc((size_t)NN * NH * 4);
    float* ad1  = (float*)alloc((size_t)NN * NH * 4);
    float* m1   = (float*)alloc((size_t)NN * NH * 4);
    float* rd1  = (float*)alloc((size_t)NN * NH * 4);
    float* as2  = (float*)alloc((size_t)NN * 4);
    float* ad2  = (float*)alloc((size_t)NN * 4);
    float* m2   = (float*)alloc((size_t)NN * 4);
    float* rd2  = (float*)alloc((size_t)NN * 4);
    int*   cnt  = (int*)alloc((size_t)NN * 4);
    int*   esrc = (int*)alloc((size_t)NN * CAP * 4);

    hipMemsetAsync(cnt, 0, (size_t)NN * 4, stream);

    // ---- bucket CSR build + input conversion/packing ----
    k_scatter<<<(ET + 255) / 256, 256, 0, stream>>>(ei, cnt, esrc);
    k_cvt<<<(NN * FIN / 8 + 255) / 256, 256, 0, stream>>>(x, xb, NN * FIN);
    k_pack<<<(2 * 8 * 8 * 64 + 255) / 256, 256, 0, stream>>>(W1, Bp1, HIDC, 8, 2 * 8 * 8 * 64);
    k_pack<<<(1 * 8 * 4 * 64 + 255) / 256, 256, 0, stream>>>(W2, Bp2, OC, 4, 1 * 8 * 4 * 64);

    // ---- layer 1 ----
    k_gemm_mfma<8><<<dim3(256, 2), 256, 0, stream>>>(xb, Bp1, h1, HIDC);
    k_alpha1<<<NN, 256, 0, stream>>>(h1, aS1, aD1, as1, ad1);
    k_attn<NH><<<(NN + 255) / 256, 256, 0, stream>>>(cnt, esrc, as1, ad1, m1, rd1);
    k_agg1g<<<(NN + 3) / 4, 256, 0, stream>>>(cnt, esrc, h1, as1, ad1, m1, rd1, b1, act1b);

    // ---- layer 2 ----
    k_gemm_mfma<4><<<dim3(512, 1), 256, 0, stream>>>(act1b, Bp2, h2, OC);
    k_alpha2<<<(NN + 3) / 4, 256, 0, stream>>>(h2, aS2, aD2, as2, ad2);
    k_attn<1><<<(NN + 255) / 256, 256, 0, stream>>>(cnt, esrc, as2, ad2, m2, rd2);
    k_agg2g<<<(NN + 3) / 4, 256, 0, stream>>>(cnt, esrc, h2, as2, ad2, m2, rd2, b2, out);
}

// Round 5
// 377.829 us; speedup vs baseline: 4.0137x; 1.1275x over previous
//
#include <hip/hip_runtime.h>
#include <math.h>

#define NN 50000
#define NE 800000
#define ET (NE + NN)
#define FIN 256
#define HIDC 256
#define OC 64
#define NH 4
#define NEG 0.2f
#define CAP 64   // lane-per-edge; deg ~ Poisson(17)+1, P(deg>64) ~ 1e-14
#define NSTRIPES (NN / 16)  // 3125

typedef __attribute__((ext_vector_type(8))) short bf16x8;
typedef __attribute__((ext_vector_type(4))) float f32x4;

__device__ __forceinline__ unsigned short f2bf(float f) {
    unsigned u = __float_as_uint(f);
    unsigned r = (u + 0x7FFFu + ((u >> 16) & 1u)) >> 16;
    return (unsigned short)r;
}
__device__ __forceinline__ float bf2f(unsigned short u) {
    return __uint_as_float(((unsigned)u) << 16);
}

// ---- fused histogram + bucket scatter ----
__global__ void k_scatter(const int* __restrict__ ei, int* __restrict__ cnt,
                          int* __restrict__ esrc) {
    int e = blockIdx.x * blockDim.x + threadIdx.x;
    if (e >= ET) return;
    int s, d;
    if (e < NE) { s = ei[e]; d = ei[NE + e]; } else { s = d = e - NE; }
    int k = atomicAdd(&cnt[d], 1);
    if (k < CAP) esrc[(size_t)d * CAP + k] = s;
}

// ---- f32 -> bf16 convert ----
__global__ void k_cvt(const float* __restrict__ x, unsigned short* __restrict__ xb,
                      int n) {
    int i = (blockIdx.x * 256 + threadIdx.x) * 8;
    if (i >= n) return;
    float4 f0 = *(const float4*)&x[i];
    float4 f1 = *(const float4*)&x[i + 4];
    uint4 o;
    o.x = (unsigned)f2bf(f0.x) | ((unsigned)f2bf(f0.y) << 16);
    o.y = (unsigned)f2bf(f0.z) | ((unsigned)f2bf(f0.w) << 16);
    o.z = (unsigned)f2bf(f1.x) | ((unsigned)f2bf(f1.y) << 16);
    o.w = (unsigned)f2bf(f1.z) | ((unsigned)f2bf(f1.w) << 16);
    *(uint4*)&xb[i] = o;
}

// ---- pack W [256][N] f32 -> MFMA B-fragment order bf16 ----
__global__ void k_pack(const float* __restrict__ W, unsigned short* __restrict__ Bp,
                       int N, int NTL, int total) {
    int t = blockIdx.x * 256 + threadIdx.x;
    if (t >= total) return;
    int lane = t & 63;
    int ntl = (t >> 6) % NTL;
    int ks = ((t >> 6) / NTL) & 7;
    int hy = t / (64 * NTL * 8);
    int col = hy * NTL * 16 + ntl * 16 + (lane & 15);
    int k0 = ks * 32 + (lane >> 4) * 8;
#pragma unroll
    for (int i = 0; i < 8; i++) Bp[(size_t)t * 8 + i] = f2bf(W[(k0 + i) * N + col]);
}

// ---- bf16 MFMA GEMM, bf16 output ----
template <int NTL>
__global__ void __launch_bounds__(256) k_gemm_mfma(const unsigned short* __restrict__ A,
                                                   const unsigned short* __restrict__ Bp,
                                                   unsigned short* __restrict__ D, int N) {
    constexpr int TOT = 8 * NTL * 64 * 8;
    __shared__ unsigned short lds[TOT];
    const unsigned short* src = Bp + (size_t)blockIdx.y * TOT;
    for (int i = threadIdx.x * 8; i < TOT; i += 256 * 8)
        *(uint4*)&lds[i] = *(const uint4*)&src[i];
    __syncthreads();
    int wave = threadIdx.x >> 6, lane = threadIdx.x & 63;
    int l15 = lane & 15, lh = lane >> 4;
    int coloff = blockIdx.y * NTL * 16;
    for (int st = blockIdx.x * 4 + wave; st < NSTRIPES; st += gridDim.x * 4) {
        const unsigned short* arow = A + (size_t)(st * 16 + l15) * 256 + lh * 8;
        f32x4 acc[NTL];
#pragma unroll
        for (int t = 0; t < NTL; t++) acc[t] = (f32x4){0.f, 0.f, 0.f, 0.f};
#pragma unroll
        for (int ks = 0; ks < 8; ks++) {
            bf16x8 a = *(const bf16x8*)(arow + ks * 32);
#pragma unroll
            for (int nt = 0; nt < NTL; nt++) {
                bf16x8 b = *(const bf16x8*)&lds[((size_t)(ks * NTL + nt) * 64 + lane) * 8];
                acc[nt] = __builtin_amdgcn_mfma_f32_16x16x32_bf16(a, b, acc[nt], 0, 0, 0);
            }
        }
        unsigned short* dbase = D + (size_t)st * 16 * N + coloff;
#pragma unroll
        for (int nt = 0; nt < NTL; nt++)
#pragma unroll
            for (int r = 0; r < 4; r++)
                dbase[(lh * 4 + r) * N + nt * 16 + l15] = f2bf(acc[nt][r]);
    }
}

// ============ alpha dot products (bf16 h) ============

__global__ void k_alpha1(const unsigned short* __restrict__ h, const float* __restrict__ a_s,
                         const float* __restrict__ a_d, float* __restrict__ as,
                         float* __restrict__ ad) {
    int n = blockIdx.x;
    int hh = threadIdx.x >> 6;
    int c = threadIdx.x & 63;
    float hv = bf2f(h[n * HIDC + hh * 64 + c]);
    float vs = hv * a_s[hh * 64 + c];
    float vd = hv * a_d[hh * 64 + c];
    for (int off = 32; off; off >>= 1) {
        vs += __shfl_xor(vs, off);
        vd += __shfl_xor(vd, off);
    }
    if (c == 0) { as[n * NH + hh] = vs; ad[n * NH + hh] = vd; }
}

__global__ void k_alpha2(const unsigned short* __restrict__ h, const float* __restrict__ a_s,
                         const float* __restrict__ a_d, float* __restrict__ as,
                         float* __restrict__ ad) {
    int n = blockIdx.x * 4 + (threadIdx.x >> 6);
    int c = threadIdx.x & 63;
    if (n >= NN) return;
    float hv = bf2f(h[n * OC + c]);
    float vs = hv * a_s[c];
    float vd = hv * a_d[c];
    for (int off = 32; off; off >>= 1) {
        vs += __shfl_xor(vs, off);
        vd += __shfl_xor(vd, off);
    }
    if (c == 0) { as[n] = vs; ad[n] = vd; }
}

// ============ wave-per-node attention: lane = edge slot, single pass ============
// stores UNNORMALIZED w = exp(e - max); 1/sum stored per node (applied in agg epilogue)

__global__ void k_attn1(const int* __restrict__ cnt, const int* __restrict__ esrc,
                        const float* __restrict__ as, const float* __restrict__ ad,
                        float* __restrict__ watt, float* __restrict__ rden) {
    int n = blockIdx.x * 4 + (threadIdx.x >> 6);
    int j = threadIdx.x & 63;
    if (n >= NN) return;
    int deg = cnt[n];
    deg = deg < CAP ? deg : CAP;
    bool act = j < deg;
    float4 adv = *(const float4*)&ad[n * NH];
    float e0 = -INFINITY, e1 = -INFINITY, e2 = -INFINITY, e3 = -INFINITY;
    if (act) {
        int s = esrc[(size_t)n * CAP + j];
        float4 av = *(const float4*)&as[s * NH];
        e0 = av.x + adv.x; e0 = e0 > 0.f ? e0 : NEG * e0;
        e1 = av.y + adv.y; e1 = e1 > 0.f ? e1 : NEG * e1;
        e2 = av.z + adv.z; e2 = e2 > 0.f ? e2 : NEG * e2;
        e3 = av.w + adv.w; e3 = e3 > 0.f ? e3 : NEG * e3;
    }
    float m0 = e0, m1 = e1, m2 = e2, m3 = e3;
    for (int off = 32; off; off >>= 1) {
        m0 = fmaxf(m0, __shfl_xor(m0, off));
        m1 = fmaxf(m1, __shfl_xor(m1, off));
        m2 = fmaxf(m2, __shfl_xor(m2, off));
        m3 = fmaxf(m3, __shfl_xor(m3, off));
    }
    float w0 = act ? expf(e0 - m0) : 0.f;
    float w1 = act ? expf(e1 - m1) : 0.f;
    float w2 = act ? expf(e2 - m2) : 0.f;
    float w3 = act ? expf(e3 - m3) : 0.f;
    float s0 = w0, s1 = w1, s2 = w2, s3 = w3;
    for (int off = 32; off; off >>= 1) {
        s0 += __shfl_xor(s0, off);
        s1 += __shfl_xor(s1, off);
        s2 += __shfl_xor(s2, off);
        s3 += __shfl_xor(s3, off);
    }
    if (act) *(float4*)&watt[((size_t)n * CAP + j) * 4] = (float4){w0, w1, w2, w3};
    if (j == 0) {
        *(float4*)&rden[n * NH] = (float4){1.f / (s0 + 1e-16f), 1.f / (s1 + 1e-16f),
                                           1.f / (s2 + 1e-16f), 1.f / (s3 + 1e-16f)};
    }
}

__global__ void k_attn2(const int* __restrict__ cnt, const int* __restrict__ esrc,
                        const float* __restrict__ as, const float* __restrict__ ad,
                        float* __restrict__ watt, float* __restrict__ rden) {
    int n = blockIdx.x * 4 + (threadIdx.x >> 6);
    int j = threadIdx.x & 63;
    if (n >= NN) return;
    int deg = cnt[n];
    deg = deg < CAP ? deg : CAP;
    bool act = j < deg;
    float adv = ad[n];
    float e = -INFINITY;
    if (act) {
        int s = esrc[(size_t)n * CAP + j];
        e = as[s] + adv;
        e = e > 0.f ? e : NEG * e;
    }
    float m = e;
    for (int off = 32; off; off >>= 1) m = fmaxf(m, __shfl_xor(m, off));
    float w = act ? expf(e - m) : 0.f;
    float s = w;
    for (int off = 32; off; off >>= 1) s += __shfl_xor(s, off);
    if (act) watt[(size_t)n * CAP + j] = w;
    if (j == 0) rden[n] = 1.f / (s + 1e-16f);
}

// ============ aggregation: wave per node, precomputed weights, bf16 gather ============

__global__ void k_agg1g(const int* __restrict__ cnt, const int* __restrict__ esrc,
                        const unsigned short* __restrict__ h, const float* __restrict__ watt,
                        const float* __restrict__ rden, const float* __restrict__ bias,
                        unsigned short* __restrict__ out) {
    int n = blockIdx.x * 4 + (threadIdx.x >> 6);
    int c = threadIdx.x & 63;
    if (n >= NN) return;
    float acc0 = 0.f, acc1 = 0.f, acc2 = 0.f, acc3 = 0.f;
    int deg = cnt[n];
    deg = deg < CAP ? deg : CAP;
    const int* bucket = &esrc[(size_t)n * CAP];
    const float* wbase = &watt[(size_t)n * CAP * 4];
    for (int j = 0; j < deg; j++) {
        int s = bucket[j];
        float4 w = *(const float4*)&wbase[j * 4];
        const unsigned short* hr = &h[(size_t)s * HIDC];
        acc0 += w.x * bf2f(hr[c]);
        acc1 += w.y * bf2f(hr[64 + c]);
        acc2 += w.z * bf2f(hr[128 + c]);
        acc3 += w.w * bf2f(hr[192 + c]);
    }
    float4 rd = *(const float4*)&rden[n * NH];
    float v;
    v = acc0 * rd.x + bias[c];       out[n * HIDC + c]       = f2bf(v > 0.f ? v : expm1f(v));
    v = acc1 * rd.y + bias[64 + c];  out[n * HIDC + 64 + c]  = f2bf(v > 0.f ? v : expm1f(v));
    v = acc2 * rd.z + bias[128 + c]; out[n * HIDC + 128 + c] = f2bf(v > 0.f ? v : expm1f(v));
    v = acc3 * rd.w + bias[192 + c]; out[n * HIDC + 192 + c] = f2bf(v > 0.f ? v : expm1f(v));
}

__global__ void k_agg2g(const int* __restrict__ cnt, const int* __restrict__ esrc,
                        const unsigned short* __restrict__ h, const float* __restrict__ watt,
                        const float* __restrict__ rden, const float* __restrict__ bias,
                        float* __restrict__ out) {
    int n = blockIdx.x * 4 + (threadIdx.x >> 6);
    int c = threadIdx.x & 63;
    if (n >= NN) return;
    float acc = 0.f;
    int deg = cnt[n];
    deg = deg < CAP ? deg : CAP;
    const int* bucket = &esrc[(size_t)n * CAP];
    const float* wbase = &watt[(size_t)n * CAP];
    for (int j = 0; j < deg; j++) {
        int s = bucket[j];
        acc += wbase[j] * bf2f(h[(size_t)s * OC + c]);
    }
    out[n * OC + c] = acc * rden[n] + bias[c];
}

extern "C" void kernel_launch(void* const* d_in, const int* in_sizes, int n_in,
                              void* d_out, int out_size, void* d_ws, size_t ws_size,
                              hipStream_t stream) {
    const float* x   = (const float*)d_in[0];
    const int*   ei  = (const int*)d_in[1];
    const float* W1  = (const float*)d_in[2];
    const float* aS1 = (const float*)d_in[3];
    const float* aD1 = (const float*)d_in[4];
    const float* b1  = (const float*)d_in[5];
    const float* W2  = (const float*)d_in[6];
    const float* aS2 = (const float*)d_in[7];
    const float* aD2 = (const float*)d_in[8];
    const float* b2  = (const float*)d_in[9];
    float* out = (float*)d_out;

    char* p = (char*)d_ws;
    auto alloc = [&](size_t nbytes) {
        char* r = p;
        p += (nbytes + 255) & ~(size_t)255;
        return r;
    };
    // region1: xb (25.6MB, dead after gemm1) aliased by watt1 (51.2MB, written after)
    char*           region1 = alloc((size_t)NN * CAP * 4 * 4);
    unsigned short* xb    = (unsigned short*)region1;
    float*          watt1 = (float*)region1;
    unsigned short* h1b   = (unsigned short*)alloc((size_t)NN * HIDC * 2);
    unsigned short* act1b = (unsigned short*)alloc((size_t)NN * HIDC * 2);
    unsigned short* h2b   = (unsigned short*)alloc((size_t)NN * OC * 2);
    float*          watt2 = (float*)alloc((size_t)NN * CAP * 4);
    unsigned short* Bp1   = (unsigned short*)alloc((size_t)2 * 8 * 8 * 64 * 8 * 2);
    unsigned short* Bp2   = (unsigned short*)alloc((size_t)1 * 8 * 4 * 64 * 8 * 2);
    float* as1  = (float*)alloc((size_t)NN * NH * 4);
    float* ad1  = (float*)alloc((size_t)NN * NH * 4);
    float* rd1  = (float*)alloc((size_t)NN * NH * 4);
    float* as2  = (float*)alloc((size_t)NN * 4);
    float* ad2  = (float*)alloc((size_t)NN * 4);
    float* rd2  = (float*)alloc((size_t)NN * 4);
    int*   cnt  = (int*)alloc((size_t)NN * 4);
    int*   esrc = (int*)alloc((size_t)NN * CAP * 4);

    hipMemsetAsync(cnt, 0, (size_t)NN * 4, stream);

    // ---- bucket CSR + conversions/packing ----
    k_scatter<<<(ET + 255) / 256, 256, 0, stream>>>(ei, cnt, esrc);
    k_cvt<<<(NN * FIN / 8 + 255) / 256, 256, 0, stream>>>(x, xb, NN * FIN);
    k_pack<<<(2 * 8 * 8 * 64 + 255) / 256, 256, 0, stream>>>(W1, Bp1, HIDC, 8, 2 * 8 * 8 * 64);
    k_pack<<<(1 * 8 * 4 * 64 + 255) / 256, 256, 0, stream>>>(W2, Bp2, OC, 4, 1 * 8 * 4 * 64);

    // ---- layer 1 ----
    k_gemm_mfma<8><<<dim3(256, 2), 256, 0, stream>>>(xb, Bp1, h1b, HIDC);
    k_alpha1<<<NN, 256, 0, stream>>>(h1b, aS1, aD1, as1, ad1);
    k_attn1<<<(NN + 3) / 4, 256, 0, stream>>>(cnt, esrc, as1, ad1, watt1, rd1);
    k_agg1g<<<(NN + 3) / 4, 256, 0, stream>>>(cnt, esrc, h1b, watt1, rd1, b1, act1b);

    // ---- layer 2 ----
    k_gemm_mfma<4><<<dim3(512, 1), 256, 0, stream>>>(act1b, Bp2, h2b, OC);
    k_alpha2<<<(NN + 3) / 4, 256, 0, stream>>>(h2b, aS2, aD2, as2, ad2);
    k_attn2<<<(NN + 3) / 4, 256, 0, stream>>>(cnt, esrc, as2, ad2, watt2, rd2);
    k_agg2g<<<(NN + 3) / 4, 256, 0, stream>>>(cnt, esrc, h2b, watt2, rd2, b2, out);
}

// Round 6
// 261.702 us; speedup vs baseline: 5.7947x; 1.4437x over previous
//
#include <hip/hip_runtime.h>
#include <math.h>

#define NN 50000
#define NE 800000
#define ET (NE + NN)
#define FIN 256
#define HIDC 256
#define OC 64
#define NH 4
#define NEG 0.2f
#define CAP 64   // lane-per-edge; deg ~ Poisson(17)+1, P(deg>64) ~ 1e-14
#define NSTRIPES (NN / 16)  // 3125

typedef __attribute__((ext_vector_type(8))) short bf16x8;
typedef __attribute__((ext_vector_type(4))) float f32x4;

__device__ __forceinline__ unsigned short f2bf(float f) {
    unsigned u = __float_as_uint(f);
    unsigned r = (u + 0x7FFFu + ((u >> 16) & 1u)) >> 16;
    return (unsigned short)r;
}
__device__ __forceinline__ float bf2f(unsigned short u) {
    return __uint_as_float(((unsigned)u) << 16);
}

// ---- fused histogram + bucket scatter ----
__global__ void k_scatter(const int* __restrict__ ei, int* __restrict__ cnt,
                          int* __restrict__ esrc) {
    int e = blockIdx.x * blockDim.x + threadIdx.x;
    if (e >= ET) return;
    int s, d;
    if (e < NE) { s = ei[e]; d = ei[NE + e]; } else { s = d = e - NE; }
    int k = atomicAdd(&cnt[d], 1);
    if (k < CAP) esrc[(size_t)d * CAP + k] = s;
}

// ---- f32 -> bf16 convert ----
__global__ void k_cvt(const float* __restrict__ x, unsigned short* __restrict__ xb,
                      int n) {
    int i = (blockIdx.x * 256 + threadIdx.x) * 8;
    if (i >= n) return;
    float4 f0 = *(const float4*)&x[i];
    float4 f1 = *(const float4*)&x[i + 4];
    uint4 o;
    o.x = (unsigned)f2bf(f0.x) | ((unsigned)f2bf(f0.y) << 16);
    o.y = (unsigned)f2bf(f0.z) | ((unsigned)f2bf(f0.w) << 16);
    o.z = (unsigned)f2bf(f1.x) | ((unsigned)f2bf(f1.y) << 16);
    o.w = (unsigned)f2bf(f1.z) | ((unsigned)f2bf(f1.w) << 16);
    *(uint4*)&xb[i] = o;
}

// ---- pack W [256][N] f32 -> MFMA B-fragment order bf16 ----
__global__ void k_pack(const float* __restrict__ W, unsigned short* __restrict__ Bp,
                       int N, int NTL, int total) {
    int t = blockIdx.x * 256 + threadIdx.x;
    if (t >= total) return;
    int lane = t & 63;
    int ntl = (t >> 6) % NTL;
    int ks = ((t >> 6) / NTL) & 7;
    int hy = t / (64 * NTL * 8);
    int col = hy * NTL * 16 + ntl * 16 + (lane & 15);
    int k0 = ks * 32 + (lane >> 4) * 8;
#pragma unroll
    for (int i = 0; i < 8; i++) Bp[(size_t)t * 8 + i] = f2bf(W[(k0 + i) * N + col]);
}

// ---- bf16 MFMA GEMM, bf16 output ----
template <int NTL>
__global__ void __launch_bounds__(256) k_gemm_mfma(const unsigned short* __restrict__ A,
                                                   const unsigned short* __restrict__ Bp,
                                                   unsigned short* __restrict__ D, int N) {
    constexpr int TOT = 8 * NTL * 64 * 8;
    __shared__ unsigned short lds[TOT];
    const unsigned short* src = Bp + (size_t)blockIdx.y * TOT;
    for (int i = threadIdx.x * 8; i < TOT; i += 256 * 8)
        *(uint4*)&lds[i] = *(const uint4*)&src[i];
    __syncthreads();
    int wave = threadIdx.x >> 6, lane = threadIdx.x & 63;
    int l15 = lane & 15, lh = lane >> 4;
    int coloff = blockIdx.y * NTL * 16;
    for (int st = blockIdx.x * 4 + wave; st < NSTRIPES; st += gridDim.x * 4) {
        const unsigned short* arow = A + (size_t)(st * 16 + l15) * 256 + lh * 8;
        f32x4 acc[NTL];
#pragma unroll
        for (int t = 0; t < NTL; t++) acc[t] = (f32x4){0.f, 0.f, 0.f, 0.f};
#pragma unroll
        for (int ks = 0; ks < 8; ks++) {
            bf16x8 a = *(const bf16x8*)(arow + ks * 32);
#pragma unroll
            for (int nt = 0; nt < NTL; nt++) {
                bf16x8 b = *(const bf16x8*)&lds[((size_t)(ks * NTL + nt) * 64 + lane) * 8];
                acc[nt] = __builtin_amdgcn_mfma_f32_16x16x32_bf16(a, b, acc[nt], 0, 0, 0);
            }
        }
        unsigned short* dbase = D + (size_t)st * 16 * N + coloff;
#pragma unroll
        for (int nt = 0; nt < NTL; nt++)
#pragma unroll
            for (int r = 0; r < 4; r++)
                dbase[(lh * 4 + r) * N + nt * 16 + l15] = f2bf(acc[nt][r]);
    }
}

// ============ alpha dot products (bf16 h) ============

__global__ void k_alpha1(const unsigned short* __restrict__ h, const float* __restrict__ a_s,
                         const float* __restrict__ a_d, float* __restrict__ as,
                         float* __restrict__ ad) {
    int n = blockIdx.x;
    int hh = threadIdx.x >> 6;
    int c = threadIdx.x & 63;
    float hv = bf2f(h[n * HIDC + hh * 64 + c]);
    float vs = hv * a_s[hh * 64 + c];
    float vd = hv * a_d[hh * 64 + c];
    for (int off = 32; off; off >>= 1) {
        vs += __shfl_xor(vs, off);
        vd += __shfl_xor(vd, off);
    }
    if (c == 0) { as[n * NH + hh] = vs; ad[n * NH + hh] = vd; }
}

__global__ void k_alpha2(const unsigned short* __restrict__ h, const float* __restrict__ a_s,
                         const float* __restrict__ a_d, float* __restrict__ as,
                         float* __restrict__ ad) {
    int n = blockIdx.x * 4 + (threadIdx.x >> 6);
    int c = threadIdx.x & 63;
    if (n >= NN) return;
    float hv = bf2f(h[n * OC + c]);
    float vs = hv * a_s[c];
    float vd = hv * a_d[c];
    for (int off = 32; off; off >>= 1) {
        vs += __shfl_xor(vs, off);
        vd += __shfl_xor(vd, off);
    }
    if (c == 0) { as[n] = vs; ad[n] = vd; }
}

// ============ fused attention+aggregation: wave per node ============
// prologue: lane = edge slot -> softmax weights in-register (butterfly shuffles)
// main loop: shuffle-broadcast (s, w), gather bf16 h rows, 4x unrolled

__global__ void k_agg1f(const int* __restrict__ cnt, const int* __restrict__ esrc,
                        const unsigned short* __restrict__ h, const float* __restrict__ as,
                        const float* __restrict__ ad, const float* __restrict__ bias,
                        unsigned short* __restrict__ out) {
    int n = blockIdx.x * 4 + (threadIdx.x >> 6);
    int lane = threadIdx.x & 63;
    if (n >= NN) return;
    int deg = cnt[n];
    deg = deg < CAP ? deg : CAP;
    const int* bucket = &esrc[(size_t)n * CAP];
    bool act = lane < deg;
    int myS = act ? bucket[lane] : 0;
    float4 adv = *(const float4*)&ad[n * NH];
    float e0 = -INFINITY, e1 = -INFINITY, e2 = -INFINITY, e3 = -INFINITY;
    if (act) {
        float4 av = *(const float4*)&as[myS * NH];
        e0 = av.x + adv.x; e0 = e0 > 0.f ? e0 : NEG * e0;
        e1 = av.y + adv.y; e1 = e1 > 0.f ? e1 : NEG * e1;
        e2 = av.z + adv.z; e2 = e2 > 0.f ? e2 : NEG * e2;
        e3 = av.w + adv.w; e3 = e3 > 0.f ? e3 : NEG * e3;
    }
    float m0 = e0, m1 = e1, m2 = e2, m3 = e3;
    for (int off = 32; off; off >>= 1) {
        m0 = fmaxf(m0, __shfl_xor(m0, off));
        m1 = fmaxf(m1, __shfl_xor(m1, off));
        m2 = fmaxf(m2, __shfl_xor(m2, off));
        m3 = fmaxf(m3, __shfl_xor(m3, off));
    }
    float w0 = act ? expf(e0 - m0) : 0.f;
    float w1 = act ? expf(e1 - m1) : 0.f;
    float w2 = act ? expf(e2 - m2) : 0.f;
    float w3 = act ? expf(e3 - m3) : 0.f;
    float s0 = w0, s1 = w1, s2 = w2, s3 = w3;
    for (int off = 32; off; off >>= 1) {
        s0 += __shfl_xor(s0, off);
        s1 += __shfl_xor(s1, off);
        s2 += __shfl_xor(s2, off);
        s3 += __shfl_xor(s3, off);
    }
    float r0 = 1.f / (s0 + 1e-16f), r1 = 1.f / (s1 + 1e-16f);
    float r2 = 1.f / (s2 + 1e-16f), r3 = 1.f / (s3 + 1e-16f);

    float acc0 = 0.f, acc1 = 0.f, acc2 = 0.f, acc3 = 0.f;
    int degP = (deg + 3) & ~3;  // pad lanes have w=0, s=0 (row 0 stays L1-hot)
    for (int j = 0; j < degP; j += 4) {
#pragma unroll
        for (int u = 0; u < 4; u++) {
            int s = __shfl(myS, j + u);
            float wx = __shfl(w0, j + u);
            float wy = __shfl(w1, j + u);
            float wz = __shfl(w2, j + u);
            float ww = __shfl(w3, j + u);
            const unsigned short* hr = &h[(size_t)s * HIDC];
            acc0 += wx * bf2f(hr[lane]);
            acc1 += wy * bf2f(hr[64 + lane]);
            acc2 += wz * bf2f(hr[128 + lane]);
            acc3 += ww * bf2f(hr[192 + lane]);
        }
    }
    float v;
    v = acc0 * r0 + bias[lane];       out[n * HIDC + lane]       = f2bf(v > 0.f ? v : expm1f(v));
    v = acc1 * r1 + bias[64 + lane];  out[n * HIDC + 64 + lane]  = f2bf(v > 0.f ? v : expm1f(v));
    v = acc2 * r2 + bias[128 + lane]; out[n * HIDC + 128 + lane] = f2bf(v > 0.f ? v : expm1f(v));
    v = acc3 * r3 + bias[192 + lane]; out[n * HIDC + 192 + lane] = f2bf(v > 0.f ? v : expm1f(v));
}

__global__ void k_agg2f(const int* __restrict__ cnt, const int* __restrict__ esrc,
                        const unsigned short* __restrict__ h, const float* __restrict__ as,
                        const float* __restrict__ ad, const float* __restrict__ bias,
                        float* __restrict__ out) {
    int n = blockIdx.x * 4 + (threadIdx.x >> 6);
    int lane = threadIdx.x & 63;
    if (n >= NN) return;
    int deg = cnt[n];
    deg = deg < CAP ? deg : CAP;
    const int* bucket = &esrc[(size_t)n * CAP];
    bool act = lane < deg;
    int myS = act ? bucket[lane] : 0;
    float adv = ad[n];
    float e = -INFINITY;
    if (act) {
        e = as[myS] + adv;
        e = e > 0.f ? e : NEG * e;
    }
    float m = e;
    for (int off = 32; off; off >>= 1) m = fmaxf(m, __shfl_xor(m, off));
    float w = act ? expf(e - m) : 0.f;
    float s = w;
    for (int off = 32; off; off >>= 1) s += __shfl_xor(s, off);
    float rd = 1.f / (s + 1e-16f);

    float acc = 0.f;
    int degP = (deg + 3) & ~3;
    for (int j = 0; j < degP; j += 4) {
#pragma unroll
        for (int u = 0; u < 4; u++) {
            int sj = __shfl(myS, j + u);
            float wj = __shfl(w, j + u);
            acc += wj * bf2f(h[(size_t)sj * OC + lane]);
        }
    }
    out[n * OC + lane] = acc * rd + bias[lane];
}

extern "C" void kernel_launch(void* const* d_in, const int* in_sizes, int n_in,
                              void* d_out, int out_size, void* d_ws, size_t ws_size,
                              hipStream_t stream) {
    const float* x   = (const float*)d_in[0];
    const int*   ei  = (const int*)d_in[1];
    const float* W1  = (const float*)d_in[2];
    const float* aS1 = (const float*)d_in[3];
    const float* aD1 = (const float*)d_in[4];
    const float* b1  = (const float*)d_in[5];
    const float* W2  = (const float*)d_in[6];
    const float* aS2 = (const float*)d_in[7];
    const float* aD2 = (const float*)d_in[8];
    const float* b2  = (const float*)d_in[9];
    float* out = (float*)d_out;

    char* p = (char*)d_ws;
    auto alloc = [&](size_t nbytes) {
        char* r = p;
        p += (nbytes + 255) & ~(size_t)255;
        return r;
    };
    unsigned short* xb    = (unsigned short*)alloc((size_t)NN * FIN * 2);
    unsigned short* h1b   = (unsigned short*)alloc((size_t)NN * HIDC * 2);
    unsigned short* act1b = (unsigned short*)alloc((size_t)NN * HIDC * 2);
    unsigned short* h2b   = (unsigned short*)alloc((size_t)NN * OC * 2);
    unsigned short* Bp1   = (unsigned short*)alloc((size_t)2 * 8 * 8 * 64 * 8 * 2);
    unsigned short* Bp2   = (unsigned short*)alloc((size_t)1 * 8 * 4 * 64 * 8 * 2);
    float* as1  = (float*)alloc((size_t)NN * NH * 4);
    float* ad1  = (float*)alloc((size_t)NN * NH * 4);
    float* as2  = (float*)alloc((size_t)NN * 4);
    float* ad2  = (float*)alloc((size_t)NN * 4);
    int*   cnt  = (int*)alloc((size_t)NN * 4);
    int*   esrc = (int*)alloc((size_t)NN * CAP * 4);

    hipMemsetAsync(cnt, 0, (size_t)NN * 4, stream);

    // ---- bucket CSR + conversions/packing ----
    k_scatter<<<(ET + 255) / 256, 256, 0, stream>>>(ei, cnt, esrc);
    k_cvt<<<(NN * FIN / 8 + 255) / 256, 256, 0, stream>>>(x, xb, NN * FIN);
    k_pack<<<(2 * 8 * 8 * 64 + 255) / 256, 256, 0, stream>>>(W1, Bp1, HIDC, 8, 2 * 8 * 8 * 64);
    k_pack<<<(1 * 8 * 4 * 64 + 255) / 256, 256, 0, stream>>>(W2, Bp2, OC, 4, 1 * 8 * 4 * 64);

    // ---- layer 1 ----
    k_gemm_mfma<8><<<dim3(256, 2), 256, 0, stream>>>(xb, Bp1, h1b, HIDC);
    k_alpha1<<<NN, 256, 0, stream>>>(h1b, aS1, aD1, as1, ad1);
    k_agg1f<<<(NN + 3) / 4, 256, 0, stream>>>(cnt, esrc, h1b, as1, ad1, b1, act1b);

    // ---- layer 2 ----
    k_gemm_mfma<4><<<dim3(512, 1), 256, 0, stream>>>(act1b, Bp2, h2b, OC);
    k_alpha2<<<(NN + 3) / 4, 256, 0, stream>>>(h2b, aS2, aD2, as2, ad2);
    k_agg2f<<<(NN + 3) / 4, 256, 0, stream>>>(cnt, esrc, h2b, as2, ad2, b2, out);
}

// Round 8
// 224.943 us; speedup vs baseline: 6.7416x; 1.1634x over previous
//
#include <hip/hip_runtime.h>
#include <math.h>

#define NN 50000
#define NE 800000
#define ET (NE + NN)
#define FIN 256
#define HIDC 256
#define OC 64
#define NH 4
#define NEG 0.2f
#define CAP 64   // lane-per-edge; deg ~ Poisson(17)+1, P(deg>64) ~ 1e-14
#define NSTRIPES (NN / 16)  // 3125

typedef __attribute__((ext_vector_type(8))) short bf16x8;
typedef __attribute__((ext_vector_type(4))) float f32x4;

__device__ __forceinline__ unsigned short f2bf(float f) {
    unsigned u = __float_as_uint(f);
    unsigned r = (u + 0x7FFFu + ((u >> 16) & 1u)) >> 16;
    return (unsigned short)r;
}
__device__ __forceinline__ float bflo(unsigned v) { return __uint_as_float(v << 16); }
__device__ __forceinline__ float bfhi(unsigned v) { return __uint_as_float(v & 0xffff0000u); }

// ---- fused histogram + bucket scatter ----
__global__ void k_scatter(const int* __restrict__ ei, int* __restrict__ cnt,
                          int* __restrict__ esrc) {
    int e = blockIdx.x * blockDim.x + threadIdx.x;
    if (e >= ET) return;
    int s, d;
    if (e < NE) { s = ei[e]; d = ei[NE + e]; } else { s = d = e - NE; }
    int k = atomicAdd(&cnt[d], 1);
    if (k < CAP) esrc[(size_t)d * CAP + k] = s;
}

// ---- pack W [256][N] f32 -> MFMA B-fragment order bf16 ----
__global__ void k_pack(const float* __restrict__ W, unsigned short* __restrict__ Bp,
                       int N, int NTL, int total) {
    int t = blockIdx.x * 256 + threadIdx.x;
    if (t >= total) return;
    int lane = t & 63;
    int ntl = (t >> 6) % NTL;
    int ks = ((t >> 6) / NTL) & 7;
    int hy = t / (64 * NTL * 8);
    int col = hy * NTL * 16 + ntl * 16 + (lane & 15);
    int k0 = ks * 32 + (lane >> 4) * 8;
#pragma unroll
    for (int i = 0; i < 8; i++) Bp[(size_t)t * 8 + i] = f2bf(W[(k0 + i) * N + col]);
}

// ---- bf16 MFMA GEMM; optional f32 A (in-kernel cvt) + fused PER-HEAD alpha dots ----
// NHEADS = head count of this layer's alpha arrays; each 64-col head lies entirely
// within one blockIdx.y half -> per-(row,head) result produced by exactly one wave
// -> plain store, no atomics.
template <int NTL, bool F32A, int NHEADS>
__global__ void __launch_bounds__(256) k_gemm(const void* __restrict__ Av,
                                              const unsigned short* __restrict__ Bp,
                                              unsigned short* __restrict__ D, int N,
                                              const float* __restrict__ aS,
                                              const float* __restrict__ aD,
                                              float* __restrict__ asOut,
                                              float* __restrict__ adOut) {
    constexpr int TOT = 8 * NTL * 64 * 8;
    constexpr int HPH = (NTL * 16) / 64;  // heads per column-half
    __shared__ unsigned short lds[TOT];
    const unsigned short* src = Bp + (size_t)blockIdx.y * TOT;
    for (int i = threadIdx.x * 8; i < TOT; i += 256 * 8)
        *(uint4*)&lds[i] = *(const uint4*)&src[i];
    __syncthreads();
    int wave = threadIdx.x >> 6, lane = threadIdx.x & 63;
    int l15 = lane & 15, lh = lane >> 4;
    int coloff = blockIdx.y * NTL * 16;
    float aSv[NTL], aDv[NTL];
#pragma unroll
    for (int nt = 0; nt < NTL; nt++) {
        aSv[nt] = aS[coloff + nt * 16 + l15];
        aDv[nt] = aD[coloff + nt * 16 + l15];
    }
    for (int st = blockIdx.x * 4 + wave; st < NSTRIPES; st += gridDim.x * 4) {
        f32x4 acc[NTL];
#pragma unroll
        for (int t = 0; t < NTL; t++) acc[t] = (f32x4){0.f, 0.f, 0.f, 0.f};
#pragma unroll
        for (int ks = 0; ks < 8; ks++) {
            bf16x8 a;
            if (F32A) {
                const float* arow = (const float*)Av + (size_t)(st * 16 + l15) * 256 + lh * 8 + ks * 32;
                float4 fa = *(const float4*)arow;
                float4 fb = *(const float4*)(arow + 4);
                a[0] = (short)f2bf(fa.x); a[1] = (short)f2bf(fa.y);
                a[2] = (short)f2bf(fa.z); a[3] = (short)f2bf(fa.w);
                a[4] = (short)f2bf(fb.x); a[5] = (short)f2bf(fb.y);
                a[6] = (short)f2bf(fb.z); a[7] = (short)f2bf(fb.w);
            } else {
                a = *(const bf16x8*)((const unsigned short*)Av + (size_t)(st * 16 + l15) * 256 + lh * 8 + ks * 32);
            }
#pragma unroll
            for (int nt = 0; nt < NTL; nt++) {
                bf16x8 b = *(const bf16x8*)&lds[((size_t)(ks * NTL + nt) * 64 + lane) * 8];
                acc[nt] = __builtin_amdgcn_mfma_f32_16x16x32_bf16(a, b, acc[nt], 0, 0, 0);
            }
        }
        unsigned short* dbase = D + (size_t)st * 16 * N + coloff;
#pragma unroll
        for (int nt = 0; nt < NTL; nt++)
#pragma unroll
            for (int r = 0; r < 4; r++)
                dbase[(lh * 4 + r) * N + nt * 16 + l15] = f2bf(acc[nt][r]);
        // fused per-head alpha dot-products
#pragma unroll
        for (int r = 0; r < 4; r++) {
#pragma unroll
            for (int g = 0; g < HPH; g++) {
                float ps = 0.f, pd = 0.f;
#pragma unroll
                for (int q = 0; q < 4; q++) {
                    int nt = g * 4 + q;
                    ps += acc[nt][r] * aSv[nt];
                    pd += acc[nt][r] * aDv[nt];
                }
#pragma unroll
                for (int off = 1; off < 16; off <<= 1) {
                    ps += __shfl_xor(ps, off);
                    pd += __shfl_xor(pd, off);
                }
                if (l15 == 0) {
                    int row = st * 16 + lh * 4 + r;
                    int hidx = blockIdx.y * HPH + g;
                    asOut[row * NHEADS + hidx] = ps;
                    adOut[row * NHEADS + hidx] = pd;
                }
            }
        }
    }
}

// ============ fused attention+aggregation: wave per node ============
// layer1: lane = 4 consecutive channels of one head; weights via per-wave LDS table

__global__ void k_agg1f(const int* __restrict__ cnt, const int* __restrict__ esrc,
                        const unsigned short* __restrict__ h, const float* __restrict__ as,
                        const float* __restrict__ ad, const float* __restrict__ bias,
                        unsigned short* __restrict__ out) {
    __shared__ float wlds[4][64][4];
    int wave = threadIdx.x >> 6;
    int n = blockIdx.x * 4 + wave;
    int lane = threadIdx.x & 63;
    if (n >= NN) return;
    int deg = cnt[n];
    deg = deg < CAP ? deg : CAP;
    const int* bucket = &esrc[(size_t)n * CAP];
    bool act = lane < deg;
    int myS = act ? bucket[lane] : 0;
    float4 adv = *(const float4*)&ad[n * NH];
    float e0 = -INFINITY, e1 = -INFINITY, e2 = -INFINITY, e3 = -INFINITY;
    if (act) {
        float4 av = *(const float4*)&as[myS * NH];
        e0 = av.x + adv.x; e0 = e0 > 0.f ? e0 : NEG * e0;
        e1 = av.y + adv.y; e1 = e1 > 0.f ? e1 : NEG * e1;
        e2 = av.z + adv.z; e2 = e2 > 0.f ? e2 : NEG * e2;
        e3 = av.w + adv.w; e3 = e3 > 0.f ? e3 : NEG * e3;
    }
    float m0 = e0, m1 = e1, m2 = e2, m3 = e3;
    for (int off = 32; off; off >>= 1) {
        m0 = fmaxf(m0, __shfl_xor(m0, off));
        m1 = fmaxf(m1, __shfl_xor(m1, off));
        m2 = fmaxf(m2, __shfl_xor(m2, off));
        m3 = fmaxf(m3, __shfl_xor(m3, off));
    }
    float w0 = act ? expf(e0 - m0) : 0.f;
    float w1 = act ? expf(e1 - m1) : 0.f;
    float w2 = act ? expf(e2 - m2) : 0.f;
    float w3 = act ? expf(e3 - m3) : 0.f;
    *(float4*)&wlds[wave][lane][0] = (float4){w0, w1, w2, w3};
    float s0 = w0, s1 = w1, s2 = w2, s3 = w3;
    for (int off = 32; off; off >>= 1) {
        s0 += __shfl_xor(s0, off);
        s1 += __shfl_xor(s1, off);
        s2 += __shfl_xor(s2, off);
        s3 += __shfl_xor(s3, off);
    }
    int hh = lane >> 4;
    int cbase = hh * 64 + (lane & 15) * 4;
    float ssel = hh == 0 ? s0 : hh == 1 ? s1 : hh == 2 ? s2 : s3;
    float rsel = 1.f / (ssel + 1e-16f);
    const float* wcol = &wlds[wave][0][hh];
    const unsigned short* hb = h + cbase;
    float acc0 = 0.f, acc1 = 0.f, acc2 = 0.f, acc3 = 0.f;
    int degP = (deg + 3) & ~3;
    for (int j = 0; j < degP; j += 4) {
#pragma unroll
        for (int u = 0; u < 4; u++) {
            int s = __shfl(myS, j + u);
            float w = wcol[(j + u) * 4];
            uint2 pv = *(const uint2*)&hb[(size_t)s * HIDC];
            acc0 += w * bflo(pv.x);
            acc1 += w * bfhi(pv.x);
            acc2 += w * bflo(pv.y);
            acc3 += w * bfhi(pv.y);
        }
    }
    float4 bv = *(const float4*)&bias[cbase];
    float v0 = acc0 * rsel + bv.x; v0 = v0 > 0.f ? v0 : expm1f(v0);
    float v1 = acc1 * rsel + bv.y; v1 = v1 > 0.f ? v1 : expm1f(v1);
    float v2 = acc2 * rsel + bv.z; v2 = v2 > 0.f ? v2 : expm1f(v2);
    float v3 = acc3 * rsel + bv.w; v3 = v3 > 0.f ? v3 : expm1f(v3);
    uint2 ov;
    ov.x = (unsigned)f2bf(v0) | ((unsigned)f2bf(v1) << 16);
    ov.y = (unsigned)f2bf(v2) | ((unsigned)f2bf(v3) << 16);
    *(uint2*)&out[(size_t)n * HIDC + cbase] = ov;
}

// layer2: 4 edges per iteration (16-lane group per edge), uint2 covers 64 channels
__global__ void k_agg2f(const int* __restrict__ cnt, const int* __restrict__ esrc,
                        const unsigned short* __restrict__ h, const float* __restrict__ as,
                        const float* __restrict__ ad, const float* __restrict__ bias,
                        float* __restrict__ out) {
    __shared__ float wlds[4][64];
    int wave = threadIdx.x >> 6;
    int n = blockIdx.x * 4 + wave;
    int lane = threadIdx.x & 63;
    if (n >= NN) return;
    int deg = cnt[n];
    deg = deg < CAP ? deg : CAP;
    const int* bucket = &esrc[(size_t)n * CAP];
    bool act = lane < deg;
    int myS = act ? bucket[lane] : 0;
    float adv = ad[n];
    float e = -INFINITY;
    if (act) {
        e = as[myS] + adv;
        e = e > 0.f ? e : NEG * e;
    }
    float m = e;
    for (int off = 32; off; off >>= 1) m = fmaxf(m, __shfl_xor(m, off));
    float w = act ? expf(e - m) : 0.f;
    wlds[wave][lane] = w;
    float s = w;
    for (int off = 32; off; off >>= 1) s += __shfl_xor(s, off);
    float rd = 1.f / (s + 1e-16f);

    int sub = lane >> 4;
    int cw = (lane & 15) * 4;
    const unsigned short* hb = h + cw;
    float acc0 = 0.f, acc1 = 0.f, acc2 = 0.f, acc3 = 0.f;
    int degP = (deg + 3) & ~3;
    for (int j = 0; j < degP; j += 4) {
        int jj = j + sub;
        int sj = __shfl(myS, jj);
        float wj = wlds[wave][jj];
        uint2 pv = *(const uint2*)&hb[(size_t)sj * OC];
        acc0 += wj * bflo(pv.x);
        acc1 += wj * bfhi(pv.x);
        acc2 += wj * bflo(pv.y);
        acc3 += wj * bfhi(pv.y);
    }
#pragma unroll
    for (int off = 16; off < 64; off <<= 1) {
        acc0 += __shfl_xor(acc0, off);
        acc1 += __shfl_xor(acc1, off);
        acc2 += __shfl_xor(acc2, off);
        acc3 += __shfl_xor(acc3, off);
    }
    if (lane < 16) {
        float4 bv = *(const float4*)&bias[cw];
        float4 o;
        o.x = acc0 * rd + bv.x;
        o.y = acc1 * rd + bv.y;
        o.z = acc2 * rd + bv.z;
        o.w = acc3 * rd + bv.w;
        *(float4*)&out[(size_t)n * OC + cw] = o;
    }
}

extern "C" void kernel_launch(void* const* d_in, const int* in_sizes, int n_in,
                              void* d_out, int out_size, void* d_ws, size_t ws_size,
                              hipStream_t stream) {
    const float* x   = (const float*)d_in[0];
    const int*   ei  = (const int*)d_in[1];
    const float* W1  = (const float*)d_in[2];
    const float* aS1 = (const float*)d_in[3];
    const float* aD1 = (const float*)d_in[4];
    const float* b1  = (const float*)d_in[5];
    const float* W2  = (const float*)d_in[6];
    const float* aS2 = (const float*)d_in[7];
    const float* aD2 = (const float*)d_in[8];
    const float* b2  = (const float*)d_in[9];
    float* out = (float*)d_out;

    char* p = (char*)d_ws;
    auto alloc = [&](size_t nbytes) {
        char* r = p;
        p += (nbytes + 255) & ~(size_t)255;
        return r;
    };
    unsigned short* h1b   = (unsigned short*)alloc((size_t)NN * HIDC * 2);
    unsigned short* act1b = (unsigned short*)alloc((size_t)NN * HIDC * 2);
    unsigned short* h2b   = (unsigned short*)alloc((size_t)NN * OC * 2);
    unsigned short* Bp1   = (unsigned short*)alloc((size_t)2 * 8 * 8 * 64 * 8 * 2);
    unsigned short* Bp2   = (unsigned short*)alloc((size_t)1 * 8 * 4 * 64 * 8 * 2);
    float* as1  = (float*)alloc((size_t)NN * NH * 4);
    float* ad1  = (float*)alloc((size_t)NN * NH * 4);
    float* as2  = (float*)alloc((size_t)NN * 4);
    float* ad2  = (float*)alloc((size_t)NN * 4);
    int*   cnt  = (int*)alloc((size_t)NN * 4);
    int*   esrc = (int*)alloc((size_t)NN * CAP * 4);

    hipMemsetAsync(cnt, 0, (size_t)NN * 4, stream);

    // ---- bucket CSR + weight packing ----
    k_scatter<<<(ET + 255) / 256, 256, 0, stream>>>(ei, cnt, esrc);
    k_pack<<<(2 * 8 * 8 * 64 + 255) / 256, 256, 0, stream>>>(W1, Bp1, HIDC, 8, 2 * 8 * 8 * 64);
    k_pack<<<(1 * 8 * 4 * 64 + 255) / 256, 256, 0, stream>>>(W2, Bp2, OC, 4, 1 * 8 * 4 * 64);

    // ---- layer 1 ---- (alpha fused into gemm epilogue, per-head)
    k_gemm<8, true, NH><<<dim3(256, 2), 256, 0, stream>>>(x, Bp1, h1b, HIDC, aS1, aD1, as1, ad1);
    k_agg1f<<<(NN + 3) / 4, 256, 0, stream>>>(cnt, esrc, h1b, as1, ad1, b1, act1b);

    // ---- layer 2 ----
    k_gemm<4, false, 1><<<dim3(512, 1), 256, 0, stream>>>(act1b, Bp2, h2b, OC, aS2, aD2, as2, ad2);
    k_agg2f<<<(NN + 3) / 4, 256, 0, stream>>>(cnt, esrc, h2b, as2, ad2, b2, out);
}